// Round 4
// baseline (239.318 us; speedup 1.0000x reference)
//
#include <hip/hip_runtime.h>
#include <hip/hip_bf16.h>
#include <stdint.h>

typedef __attribute__((ext_vector_type(4))) float f32x4;
typedef __attribute__((ext_vector_type(8))) __bf16 bf16x8;
typedef __attribute__((ext_vector_type(2))) unsigned int u32x2;
typedef __attribute__((ext_vector_type(4))) unsigned int u32x4;

#define N_NODES 16384
#define F_DIM   64

__device__ inline unsigned cvtpk_bf16(float lo, float hi) {
    unsigned r;
    asm("v_cvt_pk_bf16_f32 %0, %1, %2" : "=v"(r) : "v"(lo), "v"(hi));
    return r;
}

// ---------------------------------------------------------------------------
// Kernel A: h = input @ W (fp32 compute), stored bf16 in MFMA B-frag layout:
// chunk[(kb*4+ct)*64 + l] (16B) = h[kb*32 + (l>>4)*8 + j][ct*16 + (l&15)]
// ---------------------------------------------------------------------------
__global__ __launch_bounds__(256) void dense_h(const float* __restrict__ inp,
                                               const float* __restrict__ W,
                                               short* __restrict__ hpack) {
    __shared__ float in_lds[64][64];
    __shared__ float wt_lds[64][68];
    const int t = threadIdx.x;
    const int blk = blockIdx.x;

#pragma unroll
    for (int i = 0; i < 4; ++i) {
        int n = i * 256 + t; int row = n >> 4; int c = n & 15;
        f32x4 v = *(const f32x4*)(inp + (size_t)(blk * 64 + row) * 64 + c * 4);
        *(f32x4*)(&in_lds[row][c * 4]) = v;
    }
#pragma unroll
    for (int i = 0; i < 4; ++i) {
        int n = i * 256 + t; int k = n >> 4; int c = n & 15;
        f32x4 v = *(const f32x4*)(W + k * 64 + c * 4);
        wt_lds[c * 4 + 0][k] = v.x; wt_lds[c * 4 + 1][k] = v.y;
        wt_lds[c * 4 + 2][k] = v.z; wt_lds[c * 4 + 3][k] = v.w;
    }
    __syncthreads();

#pragma unroll
    for (int cc = 0; cc < 2; ++cc) {
        int c = cc * 256 + t;
        int kbL = c >> 8; int ct = (c >> 6) & 3; int l = c & 63;
        int f  = ct * 16 + (l & 15);
        int r0 = kbL * 32 + (l >> 4) * 8;
        float acc[8] = {0, 0, 0, 0, 0, 0, 0, 0};
        for (int k = 0; k < 64; k += 4) {
            f32x4 wv = *(const f32x4*)(&wt_lds[f][k]);
#pragma unroll
            for (int j = 0; j < 8; ++j) {
                f32x4 iv = *(const f32x4*)(&in_lds[r0 + j][k]);
                acc[j] += iv.x * wv.x + iv.y * wv.y + iv.z * wv.z + iv.w * wv.w;
            }
        }
        u32x4 w4 = {cvtpk_bf16(acc[0], acc[1]), cvtpk_bf16(acc[2], acc[3]),
                    cvtpk_bf16(acc[4], acc[5]), cvtpk_bf16(acc[6], acc[7])};
        int kb = blk * 2 + kbL;
        *(u32x4*)(hpack + ((size_t)(kb * 4 + ct) * 64 + l) * 8) = w4;
    }
}

// ---------------------------------------------------------------------------
// Kernel B: partial[sp] = adj[:, k-range] @ h[k-range, :]
// BARRIER-FREE: each wave owns 16 rows and stages its adj tile into a
// wave-PRIVATE LDS chunk (ds_write -> ds_read same wave is in-order; only
// lgkmcnt waits). No s_barrier anywhere -> waves slip freely like a fill
// kernel. Low VGPR (single rv/bb buffers) -> 16 waves/CU; grid = exactly
// one residency round.
// ---------------------------------------------------------------------------
__global__ __launch_bounds__(256, 4) void spmm_adj(const float* __restrict__ adj,
                                                   const short* __restrict__ hp,
                                                   float* __restrict__ out,
                                                   int kspan) {
    const int rb = blockIdx.x;
    const int sp = blockIdx.y;
    const int k0 = sp * kspan;
    const int iters = kspan >> 6;            // K-step 64; iters even >= 4
    const int t  = threadIdx.x;
    const int wv = t >> 6;
    const int ln = t & 63;

    __shared__ short At[4][2][16 * 64];      // [wave][buf][16 rows x 64 bf16] = 16KB

    const int lr = ln >> 4;                  // 0..3
    const int lc = ln & 15;                  // 0..15
    const float* baseA = adj + (size_t)(rb * 64 + wv * 16) * N_NODES + k0 + lc * 4;

    auto ldA = [&](int tt, f32x4* rv) {      // 16 rows x 64 cols fp32, coalesced
#pragma unroll
        for (int i = 0; i < 4; ++i)
            rv[i] = *(const f32x4*)(baseA + (size_t)(i * 4 + lr) * N_NODES + tt * 64);
    };
    auto stA = [&](int buf, const f32x4* rv) {
        char* base = (char*)At[wv][buf];
#pragma unroll
        for (int i = 0; i < 4; ++i) {
            int r = i * 4 + lr;
            u32x2 w = {cvtpk_bf16(rv[i].x, rv[i].y), cvtpk_bf16(rv[i].z, rv[i].w)};
            *(u32x2*)(base + r * 128 + ((lc * 8) ^ ((r & 7) << 4))) = w;
        }
    };
    auto ldB = [&](int tt, bf16x8* b) {      // B-frags from packed h (L2/L3-hot)
        const short* h = hp + ((size_t)(k0 >> 5) + tt * 2) * 2048 + ln * 8;
#pragma unroll
        for (int ks2 = 0; ks2 < 2; ++ks2)
#pragma unroll
            for (int ct = 0; ct < 4; ++ct)
                b[ks2 * 4 + ct] = *(const bf16x8*)(h + ks2 * 2048 + ct * 512);
    };

    f32x4 acc[4] = {{0,0,0,0},{0,0,0,0},{0,0,0,0},{0,0,0,0}};
    const int abase = (ln & 15) * 128;
    const int aswz  = (ln & 7) << 4;
    const int koff  = (ln >> 4) * 16;

    auto mfmaPhase = [&](int buf, const bf16x8* b) {
        const char* base = (const char*)At[wv][buf];
#pragma unroll
        for (int ks2 = 0; ks2 < 2; ++ks2) {
            bf16x8 a = *(const bf16x8*)(base + abase + ((ks2 * 64 + koff) ^ aswz));
#pragma unroll
            for (int ct = 0; ct < 4; ++ct)
                acc[ct] = __builtin_amdgcn_mfma_f32_16x16x32_bf16(a, b[ks2 * 4 + ct], acc[ct], 0, 0, 0);
        }
    };

    f32x4 rv[4];
    bf16x8 bb[8];

    // prologue: A(0), B(0); stage A(0) -> buf0
    ldA(0, rv);
    ldB(0, bb);
    stA(0, rv);

    int tt = 0;
    for (; tt + 2 < iters; tt += 2) {
        // even half: buf0 = A(tt), bb = B(tt)
        ldA(tt + 1, rv);
        __builtin_amdgcn_sched_barrier(0);   // pin: A-issue before compute
        mfmaPhase(0, bb);
        ldB(tt + 1, bb);                     // anti-dep keeps this after the MFMAs
        stA(1, rv);
        // odd half: buf1 = A(tt+1), bb = B(tt+1)
        ldA(tt + 2, rv);
        __builtin_amdgcn_sched_barrier(0);
        mfmaPhase(1, bb);
        ldB(tt + 2, bb);
        stA(0, rv);
    }
    // tail pair: tt == iters-2
    ldA(tt + 1, rv);
    __builtin_amdgcn_sched_barrier(0);
    mfmaPhase(0, bb);
    ldB(tt + 1, bb);
    stA(1, rv);
    mfmaPhase(1, bb);

    // epilogue: C layout col=lane&15, row=(lane>>4)*4+j
    float* o = out + (size_t)sp * ((size_t)N_NODES * F_DIM);
    const int orow0 = rb * 64 + wv * 16 + (ln >> 4) * 4;
    const int col   = ln & 15;
#pragma unroll
    for (int ct = 0; ct < 4; ++ct)
#pragma unroll
        for (int j = 0; j < 4; ++j)
            o[(size_t)(orow0 + j) * F_DIM + ct * 16 + col] = acc[ct][j];
}

// ---------------------------------------------------------------------------
// Kernel C: out = sum_i partial[i] + bias
// ---------------------------------------------------------------------------
__global__ __launch_bounds__(256) void reduce_add(const float* __restrict__ part,
                                                  const float* __restrict__ bias,
                                                  float* __restrict__ out, int nsp) {
    int g = blockIdx.x * 256 + threadIdx.x;
    f32x4 s = {0, 0, 0, 0};
    for (int i = 0; i < nsp; ++i)
        s += *(const f32x4*)(part + (size_t)i * ((size_t)N_NODES * F_DIM) + (size_t)g * 4);
    f32x4 bv = *(const f32x4*)(bias + ((g * 4) & 63));
    *(f32x4*)(out + (size_t)g * 4) = s + bv;
}

extern "C" void kernel_launch(void* const* d_in, const int* in_sizes, int n_in,
                              void* d_out, int out_size, void* d_ws, size_t ws_size,
                              hipStream_t stream) {
    const float* inp = (const float*)d_in[0];
    const float* adj = (const float*)d_in[1];
    const float* W   = (const float*)d_in[2];
    const float* b   = (const float*)d_in[3];
    float* out = (float*)d_out;

    char*  ws = (char*)d_ws;
    const size_t HP = (size_t)N_NODES * F_DIM * sizeof(short);   // 2 MB packed bf16 h
    short* hpack = (short*)ws;
    float* partial = (float*)(ws + HP);
    const size_t P1 = (size_t)N_NODES * F_DIM * sizeof(float);   // 4 MB per partial

    dense_h<<<N_NODES / 64, 256, 0, stream>>>(inp, W, hpack);

    if (ws_size >= HP + 4 * P1) {
        dim3 g(N_NODES / 64, 4);             // 1024 blocks = one full residency round
        spmm_adj<<<g, 256, 0, stream>>>(adj, hpack, partial, N_NODES / 4);
        reduce_add<<<(N_NODES * F_DIM) / 1024, 256, 0, stream>>>(partial, b, out, 4);
    } else if (ws_size >= HP + P1) {
        dim3 g(N_NODES / 64, 1);
        spmm_adj<<<g, 256, 0, stream>>>(adj, hpack, partial, N_NODES);
        reduce_add<<<(N_NODES * F_DIM) / 1024, 256, 0, stream>>>(partial, b, out, 1);
    } else {
        dim3 g(N_NODES / 64, 1);
        spmm_adj<<<g, 256, 0, stream>>>(adj, hpack, out, N_NODES);
        reduce_add<<<(N_NODES * F_DIM) / 1024, 256, 0, stream>>>(out, b, out, 1);
    }
}